// Round 4
// baseline (121.337 us; speedup 1.0000x reference)
//
#include <hip/hip_runtime.h>

#define D_MODEL 768
#define BN 64
#define LN_EPS 1e-5f

typedef __attribute__((ext_vector_type(8))) short bf16x8;
typedef __attribute__((ext_vector_type(4))) float f32x4;

// RTNE float -> bf16 bits
static __device__ __forceinline__ unsigned short f2bf(float f) {
    unsigned int u = __float_as_uint(f);
    u = (u + 0x7FFFu + ((u >> 16) & 1u)) >> 16;
    return (unsigned short)u;
}

// Fold LayerNorm affine into the down-projection:
//   wd2[k,d] = wd[k,d] * ln_w[d]          (bf16)
//   S[k]     = sum_d wd2[k,d]             (f32)
//   bd2[k]   = b_down[k] + sum_d wd[k,d]*ln_b[d]
// down_pre[t,k] = rstd[t]*(x_bf[t,:]@wd2[k,:] - mu[t]*S[k]) + bd2[k]
__global__ void prep(const float* __restrict__ wd, const float* __restrict__ ln_w,
                     const float* __restrict__ ln_b, const float* __restrict__ b_down,
                     const float* __restrict__ wu,
                     unsigned short* __restrict__ wd2_b, unsigned short* __restrict__ wu_b,
                     float* __restrict__ S, float* __restrict__ bd2) {
    const int k = blockIdx.x;    // 0..63
    const int t = threadIdx.x;   // 0..63
    float s = 0.f, sb = 0.f;
    #pragma unroll
    for (int i = 0; i < 12; ++i) {
        const int d = t + 64 * i;
        const float w0 = wd[k * D_MODEL + d];
        const float w2 = w0 * ln_w[d];
        wd2_b[k * D_MODEL + d] = f2bf(w2);
        s  += w2;
        sb += w0 * ln_b[d];
    }
    #pragma unroll
    for (int off = 1; off < 64; off <<= 1) {
        s  += __shfl_xor(s, off);
        sb += __shfl_xor(sb, off);
    }
    if (t == 0) { S[k] = s; bd2[k] = b_down[k] + sb; }
    #pragma unroll
    for (int i = 0; i < 12; ++i) {
        const int idx = (k * 12 + i) * BN + t;
        wu_b[idx] = f2bf(wu[idx]);
    }
}

__global__ __launch_bounds__(256, 8) void adapter_kernel(
    const float* __restrict__ x,
    const unsigned short* __restrict__ wd2_b, const float* __restrict__ S,
    const float* __restrict__ bd2,
    const unsigned short* __restrict__ wu_b, const float* __restrict__ b_up,
    float* __restrict__ out)
{
    // only LDS: the 16x64 bf16 down-tile for the GEMM1->GEMM2 transpose
    __shared__ __align__(16) unsigned short sDown[16][72];

    const int tid  = threadIdx.x;
    const int lane = tid & 63;
    const int w    = tid >> 6;       // wave 0..3
    const int kg   = lane >> 4;      // 0..3
    const int l16  = lane & 15;
    const size_t gt0 = (size_t)blockIdx.x * 16;

    // ---------- Fused: stream x -> {stats, bf16 A-frags}; GEMM1 (16 cols/wave) ----------
    const float* xrow = x + (gt0 + l16) * D_MODEL;   // lane owns row l16, kg-th 8-chunk
    const unsigned short* bp = wd2_b + (size_t)(w * 16 + l16) * D_MODEL + kg * 8;
    f32x4 acc1g = {0.f, 0.f, 0.f, 0.f};
    float sum = 0.f, sq = 0.f;
    #pragma unroll 6
    for (int ks = 0; ks < D_MODEL / 32; ++ks) {
        const float4 v0 = *(const float4*)(xrow + ks * 32 + kg * 8);
        const float4 v1 = *(const float4*)(xrow + ks * 32 + kg * 8 + 4);
        sum += (v0.x + v0.y) + (v0.z + v0.w) + (v1.x + v1.y) + (v1.z + v1.w);
        sq  += (v0.x*v0.x + v0.y*v0.y) + (v0.z*v0.z + v0.w*v0.w)
             + (v1.x*v1.x + v1.y*v1.y) + (v1.z*v1.z + v1.w*v1.w);
        bf16x8 a;
        a[0] = (short)f2bf(v0.x); a[1] = (short)f2bf(v0.y);
        a[2] = (short)f2bf(v0.z); a[3] = (short)f2bf(v0.w);
        a[4] = (short)f2bf(v1.x); a[5] = (short)f2bf(v1.y);
        a[6] = (short)f2bf(v1.z); a[7] = (short)f2bf(v1.w);
        const bf16x8 b = *(const bf16x8*)(bp + ks * 32);
        acc1g = __builtin_amdgcn_mfma_f32_16x16x32_bf16(a, b, acc1g, 0, 0, 0);
    }
    // full-row stats: combine the 4 kg-lanes sharing l16
    sum += __shfl_xor(sum, 16);  sum += __shfl_xor(sum, 32);
    sq  += __shfl_xor(sq, 16);   sq  += __shfl_xor(sq, 32);
    const float mu_own = sum * (1.f / D_MODEL);
    const float rs_own = rsqrtf(sq * (1.f / D_MODEL) - mu_own * mu_own + LN_EPS);

    // epilogue: lane holds G[token=kg*4+r][col = w*16 + l16]
    {
        const int c = w * 16 + l16;
        const float Sc = S[c], bd = bd2[c];
        #pragma unroll
        for (int r = 0; r < 4; ++r) {
            const int t = kg * 4 + r;
            const float mu_t = __shfl(mu_own, t);   // lane t (l16==t) holds row t's stats
            const float rs_t = __shfl(rs_own, t);
            float v = rs_t * (acc1g[r] - mu_t * Sc) + bd;
            sDown[t][c] = f2bf(v > 0.f ? v : 0.f);
        }
    }
    __syncthreads();   // the ONLY barrier

    // ---------- GEMM2 (swapped operands): D[outcol][token] ----------
    const bf16x8 pb0 = *(const bf16x8*)&sDown[l16][kg * 8];        // down[t=l16][k 0..31]
    const bf16x8 pb1 = *(const bf16x8*)&sDown[l16][32 + kg * 8];   // down[t=l16][k 32..63]
    const size_t rowOff = (gt0 + l16) * D_MODEL;
    #pragma unroll 4
    for (int j = 0; j < 12; ++j) {
        const int colBase = (4 * j + w) * 16;
        const unsigned short* wp = wu_b + (size_t)(colBase + l16) * BN;
        const bf16x8 a0 = *(const bf16x8*)(wp + kg * 8);           // wu[n=colBase+l16][k 0..31]
        const bf16x8 a1 = *(const bf16x8*)(wp + 32 + kg * 8);
        f32x4 acc = {0.f, 0.f, 0.f, 0.f};
        acc = __builtin_amdgcn_mfma_f32_16x16x32_bf16(a0, pb0, acc, 0, 0, 0);
        acc = __builtin_amdgcn_mfma_f32_16x16x32_bf16(a1, pb1, acc, 0, 0, 0);
        // lane holds out[token=l16][cols colBase+kg*4 .. +3] -> float4
        const int oc = colBase + kg * 4;
        const float4 bu = *(const float4*)(b_up + oc);
        const size_t idx = rowOff + oc;
        const float4 xv = *(const float4*)(x + idx);
        float4 o;
        o.x = acc[0] + bu.x + xv.x;
        o.y = acc[1] + bu.y + xv.y;
        o.z = acc[2] + bu.z + xv.z;
        o.w = acc[3] + bu.w + xv.w;
        *(float4*)(out + idx) = o;
    }
}

extern "C" void kernel_launch(void* const* d_in, const int* in_sizes, int n_in,
                              void* d_out, int out_size, void* d_ws, size_t ws_size,
                              hipStream_t stream) {
    const float* x      = (const float*)d_in[0];
    const float* ln_w   = (const float*)d_in[1];
    const float* ln_b   = (const float*)d_in[2];
    const float* w_down = (const float*)d_in[3];
    const float* b_down = (const float*)d_in[4];
    const float* w_up   = (const float*)d_in[5];
    const float* b_up   = (const float*)d_in[6];
    float* out = (float*)d_out;

    unsigned short* wd2_b = (unsigned short*)d_ws;               // 64*768 ush
    unsigned short* wu_b  = wd2_b + BN * D_MODEL;                // 768*64 ush
    float* S   = (float*)((char*)d_ws + 2 * BN * D_MODEL * sizeof(unsigned short));
    float* bd2 = S + BN;

    prep<<<BN, 64, 0, stream>>>(w_down, ln_w, ln_b, b_down, w_up, wd2_b, wu_b, S, bd2);

    const int tokens = in_sizes[0] / D_MODEL;   // 32768
    const int grid = tokens / 16;               // 2048
    adapter_kernel<<<grid, 256, 0, stream>>>(x, wd2_b, S, bd2, wu_b, b_up, out);
}

// Round 5
// 108.206 us; speedup vs baseline: 1.1214x; 1.1214x over previous
//
#include <hip/hip_runtime.h>

#define D_MODEL 768
#define BN 64
#define LN_EPS 1e-5f

typedef __attribute__((ext_vector_type(8))) short bf16x8;
typedef __attribute__((ext_vector_type(4))) float f32x4;

// RTNE float -> bf16 bits
static __device__ __forceinline__ unsigned short f2bf(float f) {
    unsigned int u = __float_as_uint(f);
    u = (u + 0x7FFFu + ((u >> 16) & 1u)) >> 16;
    return (unsigned short)u;
}

// Fold LayerNorm affine into the down-projection:
//   wd2[k,d] = wd[k,d] * ln_w[d]          (bf16)
//   S[k]     = sum_d wd2[k,d]             (f32)
//   bd2[k]   = b_down[k] + sum_d wd[k,d]*ln_b[d]
// down_pre[t,k] = rstd[t]*(x_bf[t,:]@wd2[k,:] - mu[t]*S[k]) + bd2[k]
__global__ void prep(const float* __restrict__ wd, const float* __restrict__ ln_w,
                     const float* __restrict__ ln_b, const float* __restrict__ b_down,
                     const float* __restrict__ wu,
                     unsigned short* __restrict__ wd2_b, unsigned short* __restrict__ wu_b,
                     float* __restrict__ S, float* __restrict__ bd2) {
    const int k = blockIdx.x;    // 0..63
    const int t = threadIdx.x;   // 0..63
    float s = 0.f, sb = 0.f;
    #pragma unroll
    for (int i = 0; i < 12; ++i) {
        const int d = t + 64 * i;
        const float w0 = wd[k * D_MODEL + d];
        const float w2 = w0 * ln_w[d];
        wd2_b[k * D_MODEL + d] = f2bf(w2);
        s  += w2;
        sb += w0 * ln_b[d];
    }
    #pragma unroll
    for (int off = 1; off < 64; off <<= 1) {
        s  += __shfl_xor(s, off);
        sb += __shfl_xor(sb, off);
    }
    if (t == 0) { S[k] = s; bd2[k] = b_down[k] + sb; }
    #pragma unroll
    for (int i = 0; i < 12; ++i) {
        const int idx = (k * 12 + i) * BN + t;
        wu_b[idx] = f2bf(wu[idx]);
    }
}

__global__ __launch_bounds__(256, 5) void adapter_kernel(
    const float* __restrict__ x,
    const unsigned short* __restrict__ wd2_b, const float* __restrict__ S,
    const float* __restrict__ bd2,
    const unsigned short* __restrict__ wu_b, const float* __restrict__ b_up,
    float* __restrict__ out)
{
    __shared__ __align__(16) unsigned short sX[16][776];     // bf16 x tile (24.8 KB)
    __shared__ __align__(16) unsigned short sDown[16][72];   // bf16 down tile
    __shared__ float sS[16][4];                              // partial sums per (token, wave)
    __shared__ float sQ[16][4];                              // partial sumsq

    const int tid  = threadIdx.x;
    const int lane = tid & 63;
    const int w    = tid >> 6;       // wave 0..3
    const int kg   = lane >> 4;      // 0..3
    const int l16  = lane & 15;
    const size_t gt0 = (size_t)blockIdx.x * 16;

    // ---------- Phase 1: single coalesced x pass ----------
    // Thread loads the exact 48 floats it needs for phase-3 residual:
    // row l16, cols {16*(4j+w) + 4*kg + 0..3}, j = 0..11.
    // Per wave-instr: 16 rows x one full 64B line each -> 16 lines, fully used.
    const float* xrow = x + (gt0 + l16) * D_MODEL;
    float4 xr[12];
    float sum = 0.f, sq = 0.f;
    #pragma unroll
    for (int j = 0; j < 12; ++j) {
        xr[j] = *(const float4*)(xrow + 16 * (4 * j + w) + 4 * kg);
        sum += (xr[j].x + xr[j].y) + (xr[j].z + xr[j].w);
        sq  += (xr[j].x * xr[j].x + xr[j].y * xr[j].y)
             + (xr[j].z * xr[j].z + xr[j].w * xr[j].w);
        ushort4 o;
        o.x = f2bf(xr[j].x); o.y = f2bf(xr[j].y);
        o.z = f2bf(xr[j].z); o.w = f2bf(xr[j].w);
        *(ushort4*)&sX[l16][16 * (4 * j + w) + 4 * kg] = o;
    }
    // reduce over kg (lanes sharing l16): partial covers 192 cols of row l16
    sum += __shfl_xor(sum, 16);  sum += __shfl_xor(sum, 32);
    sq  += __shfl_xor(sq, 16);   sq  += __shfl_xor(sq, 32);
    if (kg == 0) { sS[l16][w] = sum; sQ[l16][w] = sq; }
    __syncthreads();

    // ---------- Phase 2: GEMM1 (16 down-cols per wave) ----------
    // full-row stats for token l16 (broadcast LDS reads)
    const float4 ps = *(const float4*)&sS[l16][0];
    const float4 pq = *(const float4*)&sQ[l16][0];
    const float fsum = (ps.x + ps.y) + (ps.z + ps.w);
    const float fsq  = (pq.x + pq.y) + (pq.z + pq.w);
    const float mu_own = fsum * (1.f / D_MODEL);
    const float rs_own = rsqrtf(fsq * (1.f / D_MODEL) - mu_own * mu_own + LN_EPS);

    {
        const int c = w * 16 + l16;          // down-col 0..63
        const unsigned short* bp = wd2_b + (size_t)c * D_MODEL + kg * 8;
        f32x4 acc = {0.f, 0.f, 0.f, 0.f};
        #pragma unroll
        for (int ks = 0; ks < D_MODEL / 32; ++ks) {
            const bf16x8 a = *(const bf16x8*)&sX[l16][ks * 32 + kg * 8];
            const bf16x8 b = *(const bf16x8*)(bp + ks * 32);
            acc = __builtin_amdgcn_mfma_f32_16x16x32_bf16(a, b, acc, 0, 0, 0);
        }
        const float Sc = S[c], bd = bd2[c];
        #pragma unroll
        for (int r = 0; r < 4; ++r) {
            const int t = kg * 4 + r;
            const float mu_t = __shfl(mu_own, t);   // lane t holds token t's stats
            const float rs_t = __shfl(rs_own, t);
            float v = rs_t * (acc[r] - mu_t * Sc) + bd;
            sDown[t][c] = f2bf(v > 0.f ? v : 0.f);
        }
    }
    __syncthreads();

    // ---------- Phase 3: GEMM2 (swapped): D[outcol][token], residual from regs ----------
    const bf16x8 pb0 = *(const bf16x8*)&sDown[l16][kg * 8];        // down[t=l16][k 0..31]
    const bf16x8 pb1 = *(const bf16x8*)&sDown[l16][32 + kg * 8];   // down[t=l16][k 32..63]
    const size_t rowOff = (gt0 + l16) * D_MODEL;
    #pragma unroll 4
    for (int j = 0; j < 12; ++j) {
        const int colBase = (4 * j + w) * 16;
        const unsigned short* wp = wu_b + (size_t)(colBase + l16) * BN;
        const bf16x8 a0 = *(const bf16x8*)(wp + kg * 8);           // wu[n=colBase+l16][k 0..31]
        const bf16x8 a1 = *(const bf16x8*)(wp + 32 + kg * 8);
        f32x4 acc = {0.f, 0.f, 0.f, 0.f};
        acc = __builtin_amdgcn_mfma_f32_16x16x32_bf16(a0, pb0, acc, 0, 0, 0);
        acc = __builtin_amdgcn_mfma_f32_16x16x32_bf16(a1, pb1, acc, 0, 0, 0);
        // lane holds out[token=l16][cols colBase + kg*4 .. +3] == xr[j]'s cols
        const int oc = colBase + kg * 4;
        const float4 bu = *(const float4*)(b_up + oc);
        float4 o;
        o.x = acc[0] + bu.x + xr[j].x;
        o.y = acc[1] + bu.y + xr[j].y;
        o.z = acc[2] + bu.z + xr[j].z;
        o.w = acc[3] + bu.w + xr[j].w;
        *(float4*)(out + rowOff + oc) = o;
    }
}

extern "C" void kernel_launch(void* const* d_in, const int* in_sizes, int n_in,
                              void* d_out, int out_size, void* d_ws, size_t ws_size,
                              hipStream_t stream) {
    const float* x      = (const float*)d_in[0];
    const float* ln_w   = (const float*)d_in[1];
    const float* ln_b   = (const float*)d_in[2];
    const float* w_down = (const float*)d_in[3];
    const float* b_down = (const float*)d_in[4];
    const float* w_up   = (const float*)d_in[5];
    const float* b_up   = (const float*)d_in[6];
    float* out = (float*)d_out;

    unsigned short* wd2_b = (unsigned short*)d_ws;               // 64*768 ush
    unsigned short* wu_b  = wd2_b + BN * D_MODEL;                // 768*64 ush
    float* S   = (float*)((char*)d_ws + 2 * BN * D_MODEL * sizeof(unsigned short));
    float* bd2 = S + BN;

    prep<<<BN, 64, 0, stream>>>(w_down, ln_w, ln_b, b_down, w_up, wd2_b, wu_b, S, bd2);

    const int tokens = in_sizes[0] / D_MODEL;   // 32768
    const int grid = tokens / 16;               // 2048
    adapter_kernel<<<grid, 256, 0, stream>>>(x, wd2_b, S, bd2, wu_b, b_up, out);
}

// Round 6
// 50.506 us; speedup vs baseline: 2.4024x; 2.1424x over previous
//
#include <hip/hip_runtime.h>

#define D_MODEL 768
#define BN 64
#define LN_EPS 1e-5f

typedef __attribute__((ext_vector_type(8))) short bf16x8;
typedef __attribute__((ext_vector_type(4))) float f32x4;

// RTNE float -> bf16 bits
static __device__ __forceinline__ unsigned short f2bf(float f) {
    unsigned int u = __float_as_uint(f);
    u = (u + 0x7FFFu + ((u >> 16) & 1u)) >> 16;
    return (unsigned short)u;
}
static __device__ __forceinline__ float bf2f(unsigned short u) {
    return __uint_as_float(((unsigned int)u) << 16);
}

// prep: fold LN affine into wd, and re-layout BOTH weight matrices into
// MFMA-fragment-linear order so the main kernel's weight loads are
// wave-contiguous (base + lane*16B = 1KB/instr).
//   wd2_frag[((w*24+ks)*64 + kg*16+l16)*8 + e] = bf16(wd[c][d]*ln_w[d])
//     where c = w*16+l16 (down col), d = ks*32+kg*8+e
//   wu_frag [((jj*2+h)*64 + kg*16+nl)*8 + e]  = bf16(wu[n][k])
//     where n = jj*16+nl (out col), k = h*32+kg*8+e
__global__ void prep(const float* __restrict__ wd, const float* __restrict__ ln_w,
                     const float* __restrict__ ln_b, const float* __restrict__ b_down,
                     const float* __restrict__ wu,
                     unsigned short* __restrict__ wd2_frag, unsigned short* __restrict__ wu_frag,
                     float* __restrict__ S, float* __restrict__ bd2) {
    const int b = blockIdx.x;    // 0..63
    const int t = threadIdx.x;   // 0..63
    // ---- down-proj col c = b ----
    const int c = b;
    const int wv = c >> 4, cl = c & 15;
    float s = 0.f, sb = 0.f;
    #pragma unroll
    for (int i = 0; i < 12; ++i) {
        const int d = t + 64 * i;
        const float w0 = wd[c * D_MODEL + d];
        const float w2 = w0 * ln_w[d];
        s  += w2;
        sb += w0 * ln_b[d];
        const int ks = d >> 5, kg = (d >> 3) & 3, e = d & 7;
        wd2_frag[(((wv * 24 + ks) * 64) + kg * 16 + cl) * 8 + e] = f2bf(w2);
    }
    #pragma unroll
    for (int off = 1; off < 64; off <<= 1) {
        s  += __shfl_xor(s, off);
        sb += __shfl_xor(sb, off);
    }
    if (t == 0) { S[c] = s; bd2[c] = b_down[c] + sb; }
    // ---- up-proj rows n = b*12 .. b*12+11, thread t = k index ----
    #pragma unroll
    for (int i = 0; i < 12; ++i) {
        const int n = b * 12 + i;
        const float v = wu[n * BN + t];
        const int jj = n >> 4, nl = n & 15;
        const int h = t >> 5, kg = (t >> 3) & 3, e = t & 7;
        wu_frag[(((jj * 2 + h) * 64) + kg * 16 + nl) * 8 + e] = f2bf(v);
    }
}

__global__ __launch_bounds__(256, 4) void adapter_kernel(
    const float* __restrict__ x,
    const unsigned short* __restrict__ wd2_frag, const float* __restrict__ S,
    const float* __restrict__ bd2,
    const unsigned short* __restrict__ wu_frag, const float* __restrict__ b_up,
    float* __restrict__ out)
{
    // XOR-swizzled bf16 x tile: element (r, col) lives at byte
    //   r*1536 + ((col*2) ^ ((r&15)<<4))   -> column reads are 2-way (free)
    __shared__ __align__(16) unsigned short sX[16 * 768];
    __shared__ __align__(16) unsigned short sDown[16][72];
    __shared__ float sMu[16], sRs[16];

    const int tid  = threadIdx.x;
    const int lane = tid & 63;
    const int w    = tid >> 6;       // wave 0..3
    const int kg   = lane >> 4;      // 0..3
    const int l16  = lane & 15;
    const size_t gt0 = (size_t)blockIdx.x * 16;

    // ---------- Phase 1: wave-contiguous x pass (wave owns rows w*4..w*4+3) ----------
    {
        float4 v[12];
        const float* base0 = x + (gt0 + w * 4) * D_MODEL + lane * 4;
        #pragma unroll
        for (int p = 0; p < 4; ++p) {
            #pragma unroll
            for (int sg = 0; sg < 3; ++sg)
                v[p * 3 + sg] = *(const float4*)(base0 + p * D_MODEL + sg * 256);
        }
        #pragma unroll
        for (int p = 0; p < 4; ++p) {
            const int r = w * 4 + p;
            float sum = 0.f, sq = 0.f;
            #pragma unroll
            for (int sg = 0; sg < 3; ++sg) {
                const float4 f = v[p * 3 + sg];
                sum += (f.x + f.y) + (f.z + f.w);
                sq  += (f.x * f.x + f.y * f.y) + (f.z * f.z + f.w * f.w);
            }
            #pragma unroll
            for (int off = 1; off < 64; off <<= 1) {
                sum += __shfl_xor(sum, off);
                sq  += __shfl_xor(sq, off);
            }
            if (lane == 0) {
                const float mu = sum * (1.f / D_MODEL);
                sMu[r] = mu;
                sRs[r] = rsqrtf(sq * (1.f / D_MODEL) - mu * mu + LN_EPS);
            }
            #pragma unroll
            for (int sg = 0; sg < 3; ++sg) {
                const float4 f = v[p * 3 + sg];
                ushort4 o;
                o.x = f2bf(f.x); o.y = f2bf(f.y); o.z = f2bf(f.z); o.w = f2bf(f.w);
                const int bytecol = ((sg * 256 + lane * 4) * 2) ^ ((r & 15) << 4);
                *(ushort4*)((char*)&sX[r * 768] + bytecol) = o;
            }
        }
    }
    __syncthreads();

    // ---------- Phase 2: GEMM1, weights fragment-linear (contiguous 1KB loads) ----------
    {
        const int c = w * 16 + l16;          // down col
        const unsigned short* bp = wd2_frag + ((size_t)(w * 24) * 64 + lane) * 8;
        const char* sxrow = (const char*)&sX[l16 * 768];
        f32x4 acc = {0.f, 0.f, 0.f, 0.f};
        #pragma unroll
        for (int ks = 0; ks < 24; ++ks) {
            const bf16x8 a = *(const bf16x8*)(sxrow + ((ks * 64 + kg * 16) ^ (l16 << 4)));
            const bf16x8 b = *(const bf16x8*)(bp + ks * 512);
            acc = __builtin_amdgcn_mfma_f32_16x16x32_bf16(a, b, acc, 0, 0, 0);
        }
        const float Sc = S[c], bd = bd2[c];
        #pragma unroll
        for (int r = 0; r < 4; ++r) {
            const int t = kg * 4 + r;
            const float vv = sRs[t] * (acc[r] - sMu[t] * Sc) + bd;
            sDown[t][c] = f2bf(vv > 0.f ? vv : 0.f);
        }
    }
    __syncthreads();

    // ---------- Phase 3: GEMM2 swapped; residual from sX (bf16) ----------
    {
        const bf16x8 pb0 = *(const bf16x8*)&sDown[l16][kg * 8];
        const bf16x8 pb1 = *(const bf16x8*)&sDown[l16][32 + kg * 8];
        float* orow = out + (gt0 + l16) * D_MODEL;
        const char* sxrow = (const char*)&sX[l16 * 768];
        #pragma unroll 3
        for (int j = 0; j < 12; ++j) {
            const int jj = 4 * j + w;
            const unsigned short* ap = wu_frag + ((size_t)(jj * 2) * 64 + lane) * 8;
            const bf16x8 a0 = *(const bf16x8*)ap;
            const bf16x8 a1 = *(const bf16x8*)(ap + 512);
            f32x4 acc = {0.f, 0.f, 0.f, 0.f};
            acc = __builtin_amdgcn_mfma_f32_16x16x32_bf16(a0, pb0, acc, 0, 0, 0);
            acc = __builtin_amdgcn_mfma_f32_16x16x32_bf16(a1, pb1, acc, 0, 0, 0);
            const int oc = jj * 16 + kg * 4;
            const float4 bu = *(const float4*)(b_up + oc);
            const ushort4 xb = *(const ushort4*)(sxrow + ((oc * 2) ^ (l16 << 4)));
            float4 o;
            o.x = acc[0] + bu.x + bf2f(xb.x);
            o.y = acc[1] + bu.y + bf2f(xb.y);
            o.z = acc[2] + bu.z + bf2f(xb.z);
            o.w = acc[3] + bu.w + bf2f(xb.w);
            *(float4*)(orow + oc) = o;
        }
    }
}

extern "C" void kernel_launch(void* const* d_in, const int* in_sizes, int n_in,
                              void* d_out, int out_size, void* d_ws, size_t ws_size,
                              hipStream_t stream) {
    const float* x      = (const float*)d_in[0];
    const float* ln_w   = (const float*)d_in[1];
    const float* ln_b   = (const float*)d_in[2];
    const float* w_down = (const float*)d_in[3];
    const float* b_down = (const float*)d_in[4];
    const float* w_up   = (const float*)d_in[5];
    const float* b_up   = (const float*)d_in[6];
    float* out = (float*)d_out;

    unsigned short* wd2_frag = (unsigned short*)d_ws;            // 64*768 ush
    unsigned short* wu_frag  = wd2_frag + BN * D_MODEL;          // 768*64 ush
    float* S   = (float*)((char*)d_ws + 2 * BN * D_MODEL * sizeof(unsigned short));
    float* bd2 = S + BN;

    prep<<<BN, 64, 0, stream>>>(w_down, ln_w, ln_b, b_down, w_up, wd2_frag, wu_frag, S, bd2);

    const int tokens = in_sizes[0] / D_MODEL;   // 32768
    const int grid = tokens / 16;               // 2048
    adapter_kernel<<<grid, 256, 0, stream>>>(x, wd2_frag, S, bd2, wu_frag, b_up, out);
}